// Round 5
// baseline (2757.222 us; speedup 1.0000x reference)
//
#include <hip/hip_runtime.h>
#include <math.h>

#define TOKENS  32768
#define HIDDEN  2048
#define EXPERTS 64
#define TOPK    8
#define KW      256              // k per wave (K-split 8 across the block's waves)
#define BK      16               // k per fill
#define NFILL   (KW / BK)        // 16

// ---------------------------------------------------------------------------
// One fused kernel. Block = 512 thr (8 waves) owns 64 tokens; each wave
// computes the FULL 64x64 (token x expert) tile over its own K-eighth.
// Lane = (tg,eg): 8 tokens x 8 experts register tile (acc 64 VGPR).
// W: per-wave private LDS tile [16k][64e], staged from global (lane=expert
// row, coalesced float4) with transpose-on-write, double-buffered, NO
// __syncthreads in the main loop (wave-private buffers).
// A: per-lane global float2 loads; the 8 lanes of an expert-group issue the
// SAME address -> L1 merge/broadcast; lines consumed fully across one fill.
// Epilogue: 3-level LDS reduce tree over 8 wave-partials + bias, per-token
// top-8 + softmax + scatter, coalesced writes. Indices stored as floats.
// ---------------------------------------------------------------------------
__global__ __launch_bounds__(512, 4)
void router_rf(const float* __restrict__ A,
               const float* __restrict__ W,
               const float* __restrict__ bias,
               float* __restrict__ out) {
    __shared__ float smem[16384];          // 64 KB
    const int tid  = threadIdx.x;
    const int wv   = tid >> 6;             // wave 0..7 = K-eighth
    const int lane = tid & 63;
    const int g    = blockIdx.x;

    const int tg = lane & 7;               // token group: tokens tg*8..tg*8+7
    const int eg = lane >> 3;              // expert group
    const int e0 = eg * 8;                 // experts e0..e0+7

    // W staging: lane = expert row; wave-private K window
    const float* wsrc = W + (size_t)lane * HIDDEN + wv * KW;
    // A: 8 consecutive token rows for this lane's token group
    const float* abase = A + ((size_t)g * 64 + tg * 8) * HIDDEN + wv * KW;

    float* wb0 = smem + wv * 2048;         // per-wave double buffer (2 x 1024 floats)
    float* wb1 = wb0 + 1024;

    float acc[8][8];
    #pragma unroll
    for (int i = 0; i < 8; ++i)
        #pragma unroll
        for (int j = 0; j < 8; ++j) acc[i][j] = 0.f;

    float4 s0, s1, s2, s3;                 // W staging registers

    #define LOADW(f) do {                                         \
        const float* p_ = wsrc + (f) * BK;                        \
        s0 = *(const float4*)(p_ + 0);                            \
        s1 = *(const float4*)(p_ + 4);                            \
        s2 = *(const float4*)(p_ + 8);                            \
        s3 = *(const float4*)(p_ + 12);                           \
    } while (0)

    #define WRITEW(nb) do {                                       \
        (nb)[ 0*64+lane]=s0.x; (nb)[ 1*64+lane]=s0.y;             \
        (nb)[ 2*64+lane]=s0.z; (nb)[ 3*64+lane]=s0.w;             \
        (nb)[ 4*64+lane]=s1.x; (nb)[ 5*64+lane]=s1.y;             \
        (nb)[ 6*64+lane]=s1.z; (nb)[ 7*64+lane]=s1.w;             \
        (nb)[ 8*64+lane]=s2.x; (nb)[ 9*64+lane]=s2.y;             \
        (nb)[10*64+lane]=s2.z; (nb)[11*64+lane]=s2.w;             \
        (nb)[12*64+lane]=s3.x; (nb)[13*64+lane]=s3.y;             \
        (nb)[14*64+lane]=s3.z; (nb)[15*64+lane]=s3.w;             \
    } while (0)

    // prologue
    LOADW(0);
    WRITEW(wb0);

    const float* ab = abase;
    #pragma unroll 1
    for (int f = 0; f < NFILL; ++f) {
        const float* cb = (f & 1) ? wb1 : wb0;
        float*       nb = (f & 1) ? wb0 : wb1;
        if (f + 1 < NFILL) LOADW(f + 1);   // next W tile flies during compute

        #pragma unroll
        for (int m = 0; m < 8; ++m) {      // 2 k's per microstep
            float2 a[8];
            #pragma unroll
            for (int i = 0; i < 8; ++i)
                a[i] = *(const float2*)(ab + i * HIDDEN + 2 * m);
            float4 wA0 = *(const float4*)(cb + (2*m    )*64 + e0);
            float4 wA1 = *(const float4*)(cb + (2*m    )*64 + e0 + 4);
            float4 wB0 = *(const float4*)(cb + (2*m + 1)*64 + e0);
            float4 wB1 = *(const float4*)(cb + (2*m + 1)*64 + e0 + 4);
            #pragma unroll
            for (int i = 0; i < 8; ++i) {
                float ax = a[i].x, ay = a[i].y;
                acc[i][0] = fmaf(ax, wA0.x, acc[i][0]);
                acc[i][1] = fmaf(ax, wA0.y, acc[i][1]);
                acc[i][2] = fmaf(ax, wA0.z, acc[i][2]);
                acc[i][3] = fmaf(ax, wA0.w, acc[i][3]);
                acc[i][4] = fmaf(ax, wA1.x, acc[i][4]);
                acc[i][5] = fmaf(ax, wA1.y, acc[i][5]);
                acc[i][6] = fmaf(ax, wA1.z, acc[i][6]);
                acc[i][7] = fmaf(ax, wA1.w, acc[i][7]);
                acc[i][0] = fmaf(ay, wB0.x, acc[i][0]);
                acc[i][1] = fmaf(ay, wB0.y, acc[i][1]);
                acc[i][2] = fmaf(ay, wB0.z, acc[i][2]);
                acc[i][3] = fmaf(ay, wB0.w, acc[i][3]);
                acc[i][4] = fmaf(ay, wB1.x, acc[i][4]);
                acc[i][5] = fmaf(ay, wB1.y, acc[i][5]);
                acc[i][6] = fmaf(ay, wB1.z, acc[i][6]);
                acc[i][7] = fmaf(ay, wB1.w, acc[i][7]);
            }
        }
        if (f + 1 < NFILL) WRITEW(nb);
        ab += BK;
    }
    #undef LOADW
    #undef WRITEW

    // ---- reduce tree over 8 wave-partials (regions of 4096 floats) ----
    #define PWRITE(dst) do {                                                  \
        _Pragma("unroll")                                                     \
        for (int j = 0; j < 8; ++j) {                                         \
            float4 q0 = make_float4(acc[0][j],acc[1][j],acc[2][j],acc[3][j]); \
            float4 q1 = make_float4(acc[4][j],acc[5][j],acc[6][j],acc[7][j]); \
            *(float4*)((dst) + (e0+j)*64 + tg*8)     = q0;                    \
            *(float4*)((dst) + (e0+j)*64 + tg*8 + 4) = q1;                    \
        }                                                                     \
    } while (0)
    #define PADD(src) do {                                                    \
        _Pragma("unroll")                                                     \
        for (int j = 0; j < 8; ++j) {                                         \
            float4 q0 = *(const float4*)((src) + (e0+j)*64 + tg*8);           \
            float4 q1 = *(const float4*)((src) + (e0+j)*64 + tg*8 + 4);       \
            acc[0][j]+=q0.x; acc[1][j]+=q0.y; acc[2][j]+=q0.z; acc[3][j]+=q0.w;\
            acc[4][j]+=q1.x; acc[5][j]+=q1.y; acc[6][j]+=q1.z; acc[7][j]+=q1.w;\
        }                                                                     \
    } while (0)

    __syncthreads();                        // all compute done; LDS reusable
    if (wv >= 4) PWRITE(smem + (wv - 4) * 4096);
    __syncthreads();
    if (wv < 4)  PADD(smem + wv * 4096);
    __syncthreads();
    if (wv == 2 || wv == 3) PWRITE(smem + (wv - 2) * 4096);
    __syncthreads();
    if (wv < 2)  PADD(smem + wv * 4096);
    __syncthreads();
    if (wv == 1) PWRITE(smem);
    __syncthreads();
    if (wv == 0) {
        PADD(smem);
        float4 b0 = *(const float4*)(bias + e0);
        float4 b1 = *(const float4*)(bias + e0 + 4);
        float bb[8] = {b0.x,b0.y,b0.z,b0.w,b1.x,b1.y,b1.z,b1.w};
        #pragma unroll
        for (int i = 0; i < 8; ++i)
            #pragma unroll
            for (int j = 0; j < 8; ++j) acc[i][j] += bb[j];
        PWRITE(smem);                       // final logits [e][t] at region 0
    }
    #undef PWRITE
    #undef PADD

    float* scat = smem + 8192;              // [64 t][65] padded
    for (int i = tid; i < 64 * 65; i += 512) scat[i] = 0.f;
    __syncthreads();

    // ---- top-8 + softmax + scatter: one thread per token ----
    if (tid < 64) {
        const int t = tid;
        float v[64];
        #pragma unroll
        for (int e = 0; e < 64; ++e) v[e] = smem[e * 64 + t];

        float tvals[TOPK]; int tix[TOPK]; float probs[TOPK];
        unsigned long long chosen = 0ull;
        #pragma unroll
        for (int j = 0; j < TOPK; ++j) {
            float best = -INFINITY; int bi = 0;
            #pragma unroll
            for (int e = 0; e < 64; ++e) {
                bool ok = ((chosen >> e) & 1ull) == 0ull;
                if (ok && v[e] > best) { best = v[e]; bi = e; }  // strict >: lowest idx on tie
            }
            chosen |= (1ull << bi);
            tvals[j] = best; tix[j] = bi;
        }
        float m = tvals[0];
        float ssum = 0.f;
        #pragma unroll
        for (int j = 0; j < TOPK; ++j) { probs[j] = __expf(tvals[j] - m); ssum += probs[j]; }
        float inv = 1.f / ssum;
        #pragma unroll
        for (int j = 0; j < TOPK; ++j) probs[j] *= inv;

        #pragma unroll
        for (int j = 0; j < TOPK; ++j) scat[t * 65 + tix[j]] = probs[j];

        float* oidx = out + (size_t)TOKENS * EXPERTS;
        const int token = g * 64 + t;
        #pragma unroll
        for (int j = 0; j < TOPK; ++j) oidx[(size_t)token * TOPK + j] = (float)tix[j];
    }
    __syncthreads();

    // ---- coalesced score write: 64 tokens x 64 experts = 1024 float4 ----
    float* oscore = out + (size_t)g * 4096;
    #pragma unroll
    for (int p = 0; p < 2; ++p) {
        int fi  = tid + 512 * p;
        int tok = fi >> 4;
        int es  = (fi & 15) * 4;
        float4 vv;
        vv.x = scat[tok * 65 + es + 0];
        vv.y = scat[tok * 65 + es + 1];
        vv.z = scat[tok * 65 + es + 2];
        vv.w = scat[tok * 65 + es + 3];
        *(float4*)(oscore + (size_t)fi * 4) = vv;
    }
}

extern "C" void kernel_launch(void* const* d_in, const int* in_sizes, int n_in,
                              void* d_out, int out_size, void* d_ws, size_t ws_size,
                              hipStream_t stream) {
    const float* A    = (const float*)d_in[0];   // [32768, 2048] fp32
    const float* W    = (const float*)d_in[1];   // [64, 2048] fp32
    const float* bias = (const float*)d_in[2];   // [64] fp32
    float* out = (float*)d_out;                  // scores (32768*64) ++ idx (32768*8)
    (void)d_ws; (void)ws_size;

    router_rf<<<TOKENS / 64, 512, 0, stream>>>(A, W, bias, out);
}

// Round 6
// 738.720 us; speedup vs baseline: 3.7324x; 3.7324x over previous
//
#include <hip/hip_runtime.h>
#include <math.h>

#define TOKENS  32768
#define HIDDEN  2048
#define EXPERTS 64
#define TOPK    8
#define BK      32
#define NSTEP   (HIDDEN / BK)   // 64
#define LDA     68              // padded LDS row (floats); 68*4B = 16B-aligned rows

// ---------------------------------------------------------------------------
// Kernel 1: W[64][2048] -> wT[2048][64] (d_ws). Per-k expert weights become
// consecutive: lane reads wT[k][e0..e0+8) as 2 float4 (8-way lane merge, L2-hot).
// ---------------------------------------------------------------------------
__global__ void wt_transpose(const float* __restrict__ W, float* __restrict__ wT) {
    int i = blockIdx.x * 256 + threadIdx.x;   // 0..131071
    int k = i >> 6;
    int e = i & 63;
    wT[i] = W[e * HIDDEN + k];
}

// ---------------------------------------------------------------------------
// Kernel 2: fused router. 512 thr (8 waves) per 64-token group.
// Shared A-window [BK=32][68] double-buffered in LDS (transpose-on-write);
// wave wv computes k = wv*4..wv*4+4 of each window -> partial logits.
// Per-lane 8 tokens x 8 experts (acc 64 VGPR). W from global wT, rolling
// 2-k-deep prefetch (16 VGPR). One barrier per step. Epilogue: paired-wave
// LDS reduce of 8 partials + bias, top-8 + softmax + scatter, coalesced out.
// ---------------------------------------------------------------------------
__global__ __launch_bounds__(512, 4)
void router_bc(const float* __restrict__ A,
               const float* __restrict__ wT,
               const float* __restrict__ bias,
               float* __restrict__ out) {
    __shared__ float smem[12352];  // staging 2x[32][68]=4352 | epi: red0@0, red1@4096, scat@8192
    const int tid  = threadIdx.x;
    const int wv   = tid >> 6;
    const int lane = tid & 63;
    const int g    = blockIdx.x;

    const int tg = lane & 7;          // token group: tokens tg*8..tg*8+7
    const int eg = lane >> 3;
    const int e0 = eg * 8;            // experts e0..e0+7

    // staging map: thread -> (token row st, float4 chunk sc) of the window
    const int st = tid >> 3;          // 0..63
    const int sc = tid & 7;           // 0..7 -> k-offsets sc*4..sc*4+3
    const float* asrc = A + ((size_t)g * 64 + st) * HIDDEN + sc * 4;

    float* buf0 = smem;               // [32][68]
    float* buf1 = smem + BK * LDA;

    float acc[8][8];
    #pragma unroll
    for (int i = 0; i < 8; ++i)
        #pragma unroll
        for (int j = 0; j < 8; ++j) acc[i][j] = 0.f;

    #define FMA_TILE(A0, A1, W0, W1) do {                                   \
        float axx[8] = {(A0).x,(A0).y,(A0).z,(A0).w,(A1).x,(A1).y,(A1).z,(A1).w}; \
        float wxx[8] = {(W0).x,(W0).y,(W0).z,(W0).w,(W1).x,(W1).y,(W1).z,(W1).w}; \
        _Pragma("unroll")                                                   \
        for (int i_ = 0; i_ < 8; ++i_)                                      \
            _Pragma("unroll")                                               \
            for (int j_ = 0; j_ < 8; ++j_)                                  \
                acc[i_][j_] = fmaf(axx[i_], wxx[j_], acc[i_][j_]);          \
    } while (0)

    // consume (WC0,WC1) on k-row KK of cb, prefetch next W pair from PP
    #define KSTEP(cb, KK, WC0, WC1, PP) do {                                \
        const float* ar_ = (cb) + (KK) * LDA + tg * 8;                      \
        float4 a0_ = *(const float4*)(ar_);                                 \
        float4 a1_ = *(const float4*)(ar_ + 4);                             \
        float4 p0_ = *(const float4*)((PP) + e0);                           \
        float4 p1_ = *(const float4*)((PP) + e0 + 4);                       \
        FMA_TILE(a0_, a1_, WC0, WC1);                                       \
        WC0 = p0_; WC1 = p1_;                                               \
    } while (0)

    // prologue: stage window 0, prime W k0/k1
    {
        float4 sv = *(const float4*)(asrc);
        buf0[(sc * 4 + 0) * LDA + st] = sv.x;
        buf0[(sc * 4 + 1) * LDA + st] = sv.y;
        buf0[(sc * 4 + 2) * LDA + st] = sv.z;
        buf0[(sc * 4 + 3) * LDA + st] = sv.w;
    }
    const float* wp0 = wT + (size_t)(wv * 4) * 64;
    float4 wa0 = *(const float4*)(wp0 + e0);
    float4 wa1 = *(const float4*)(wp0 + e0 + 4);
    float4 wb0 = *(const float4*)(wp0 + 64 + e0);
    float4 wb1 = *(const float4*)(wp0 + 64 + e0 + 4);

    #pragma unroll 1
    for (int s = 0; s < NSTEP; ++s) {
        float* cb = (s & 1) ? buf1 : buf0;
        float* nb = (s & 1) ? buf0 : buf1;
        __syncthreads();                          // cb published

        float4 snext = make_float4(0.f, 0.f, 0.f, 0.f);
        if (s + 1 < NSTEP) snext = *(const float4*)(asrc + (s + 1) * BK);

        const float* wp  = wT + ((size_t)(s * BK) + wv * 4) * 64;            // this window
        const float* wpn = wT + ((size_t)(((s + 1) & 63) * BK) + wv * 4) * 64; // next window

        const int kb = wv * 4;
        KSTEP(cb, kb + 0, wa0, wa1, wp + 128);    // consume k0, prefetch k2
        KSTEP(cb, kb + 1, wb0, wb1, wp + 192);    // consume k1, prefetch k3
        KSTEP(cb, kb + 2, wa0, wa1, wpn);         // consume k2, prefetch next k0
        KSTEP(cb, kb + 3, wb0, wb1, wpn + 64);    // consume k3, prefetch next k1

        if (s + 1 < NSTEP) {
            nb[(sc * 4 + 0) * LDA + st] = snext.x;
            nb[(sc * 4 + 1) * LDA + st] = snext.y;
            nb[(sc * 4 + 2) * LDA + st] = snext.z;
            nb[(sc * 4 + 3) * LDA + st] = snext.w;
        }
    }
    #undef KSTEP
    #undef FMA_TILE

    // ---- reduce 8 wave-partials into red0 (+bias), paired-wave rounds ----
    float* red0 = smem;
    float* red1 = smem + 4096;
    float* scat = smem + 8192;       // [64 t][65]

    #define PWRITE(dst) do { _Pragma("unroll")                              \
        for (int j_ = 0; j_ < 8; ++j_) {                                    \
            *(float4*)((dst) + (e0 + j_) * 64 + tg * 8) =                   \
                make_float4(acc[0][j_], acc[1][j_], acc[2][j_], acc[3][j_]);\
            *(float4*)((dst) + (e0 + j_) * 64 + tg * 8 + 4) =               \
                make_float4(acc[4][j_], acc[5][j_], acc[6][j_], acc[7][j_]);\
        } } while (0)
    #define PADD(dst) do { _Pragma("unroll")                                \
        for (int j_ = 0; j_ < 8; ++j_) {                                    \
            float4 q0 = *(const float4*)((dst) + (e0 + j_) * 64 + tg * 8);  \
            float4 q1 = *(const float4*)((dst) + (e0 + j_) * 64 + tg * 8 + 4);\
            q0.x += acc[0][j_]; q0.y += acc[1][j_];                         \
            q0.z += acc[2][j_]; q0.w += acc[3][j_];                         \
            q1.x += acc[4][j_]; q1.y += acc[5][j_];                         \
            q1.z += acc[6][j_]; q1.w += acc[7][j_];                         \
            *(float4*)((dst) + (e0 + j_) * 64 + tg * 8)     = q0;           \
            *(float4*)((dst) + (e0 + j_) * 64 + tg * 8 + 4) = q1;           \
        } } while (0)

    __syncthreads();                 // all compute + last reads of buffers done
    if (wv == 0) PWRITE(red0); else if (wv == 1) PWRITE(red1);
    __syncthreads();
    if (wv == 2) PADD(red0); else if (wv == 3) PADD(red1);
    __syncthreads();
    if (wv == 4) PADD(red0); else if (wv == 5) PADD(red1);
    __syncthreads();
    if (wv == 6) PADD(red0); else if (wv == 7) PADD(red1);
    __syncthreads();
    #undef PWRITE
    #undef PADD

    // final: red0 = red0 + red1 + bias   (e = i>>6 is wave-uniform per pass)
    #pragma unroll
    for (int p = 0; p < 8; ++p) {
        int i = tid + 512 * p;
        red0[i] = red0[i] + red1[i] + bias[i >> 6];
    }
    for (int i = tid; i < 64 * 65; i += 512) scat[i] = 0.f;
    __syncthreads();

    // ---- top-8 + softmax + scatter: one thread per token ----
    if (tid < 64) {
        const int t = tid;
        float v[64];
        #pragma unroll
        for (int e = 0; e < 64; ++e) v[e] = red0[e * 64 + t];

        float tvals[TOPK]; int tix[TOPK]; float probs[TOPK];
        unsigned long long chosen = 0ull;
        #pragma unroll
        for (int j = 0; j < TOPK; ++j) {
            float best = -INFINITY; int bi = 0;
            #pragma unroll
            for (int e = 0; e < 64; ++e) {
                bool ok = ((chosen >> e) & 1ull) == 0ull;
                if (ok && v[e] > best) { best = v[e]; bi = e; }  // strict >: lowest idx on tie
            }
            chosen |= (1ull << bi);
            tvals[j] = best; tix[j] = bi;
        }
        float m = tvals[0];
        float ssum = 0.f;
        #pragma unroll
        for (int j = 0; j < TOPK; ++j) { probs[j] = __expf(tvals[j] - m); ssum += probs[j]; }
        float inv = 1.f / ssum;
        #pragma unroll
        for (int j = 0; j < TOPK; ++j) probs[j] *= inv;

        #pragma unroll
        for (int j = 0; j < TOPK; ++j) scat[t * 65 + tix[j]] = probs[j];

        float* oidx = out + (size_t)TOKENS * EXPERTS;
        const int token = g * 64 + t;
        #pragma unroll
        for (int j = 0; j < TOPK; ++j) oidx[(size_t)token * TOPK + j] = (float)tix[j];
    }
    __syncthreads();

    // ---- coalesced score write: 64 tokens x 64 experts = 1024 float4 ----
    float* oscore = out + (size_t)g * 4096;
    #pragma unroll
    for (int p = 0; p < 2; ++p) {
        int fi  = tid + 512 * p;
        int tok = fi >> 4;
        int es  = (fi & 15) * 4;
        float4 vv;
        vv.x = scat[tok * 65 + es + 0];
        vv.y = scat[tok * 65 + es + 1];
        vv.z = scat[tok * 65 + es + 2];
        vv.w = scat[tok * 65 + es + 3];
        *(float4*)(oscore + (size_t)fi * 4) = vv;
    }
}

extern "C" void kernel_launch(void* const* d_in, const int* in_sizes, int n_in,
                              void* d_out, int out_size, void* d_ws, size_t ws_size,
                              hipStream_t stream) {
    const float* A    = (const float*)d_in[0];   // [32768, 2048] fp32
    const float* W    = (const float*)d_in[1];   // [64, 2048] fp32
    const float* bias = (const float*)d_in[2];   // [64] fp32
    float* out = (float*)d_out;                  // scores (32768*64) ++ idx (32768*8)
    float* wT  = (float*)d_ws;                   // 512 KB scratch

    wt_transpose<<<512, 256, 0, stream>>>(W, wT);
    router_bc<<<TOKENS / 64, 512, 0, stream>>>(A, wT, bias, out);
}

// Round 7
// 191.921 us; speedup vs baseline: 14.3664x; 3.8491x over previous
//
#include <hip/hip_runtime.h>
#include <math.h>

#define TOKENS  32768
#define HIDDEN  2048
#define EXPERTS 64
#define TOPK    8
#define BK      32
#define NSTEP   (HIDDEN / BK)   // 64
#define LDA     68              // padded LDS row (floats); 68*4B = 16B-aligned rows

// ---------------------------------------------------------------------------
// Kernel 1: W[64][2048] -> wT[2048][64] (d_ws). Per-k expert weights become
// consecutive: lane reads wT[k][e0..e0+8) as 2 float4 (8-way lane merge, L2-hot).
// ---------------------------------------------------------------------------
__global__ void wt_transpose(const float* __restrict__ W, float* __restrict__ wT) {
    int i = blockIdx.x * 256 + threadIdx.x;   // 0..131071
    int k = i >> 6;
    int e = i & 63;
    wT[i] = W[e * HIDDEN + k];
}

// ---------------------------------------------------------------------------
// Kernel 2: fused router. 512 thr (8 waves) per 64-token group.
// Shared A-window [BK=32][68] double-buffered in LDS (transpose-on-write);
// wave wv computes k = wv*4..wv*4+4 of each window -> partial logits.
// Per-lane 8 tokens x 8 experts (acc 64 VGPR). W from global wT, rolling
// 2-k-deep prefetch (16 VGPR). One barrier per step.
// NOTE: __launch_bounds__(512, 1): arg2=4 empirically caps VGPR at 64 on this
// toolchain (r2/r4/r5 all showed VGPR_Count=64; r4/r5 spilled GBs of scratch).
// With (512,1) the ~110-reg live set fits -> 4 waves/SIMD by VGPR, no spill.
// ---------------------------------------------------------------------------
__global__ __launch_bounds__(512, 1)
void router_bc(const float* __restrict__ A,
               const float* __restrict__ wT,
               const float* __restrict__ bias,
               float* __restrict__ out) {
    __shared__ float smem[12352];  // staging 2x[32][68]=4352 | epi: red0@0, red1@4096, scat@8192
    const int tid  = threadIdx.x;
    const int wv   = tid >> 6;
    const int lane = tid & 63;
    const int g    = blockIdx.x;

    const int tg = lane & 7;          // token group: tokens tg*8..tg*8+7
    const int eg = lane >> 3;
    const int e0 = eg * 8;            // experts e0..e0+7

    // staging map: thread -> (token row st, float4 chunk sc) of the window
    const int st = tid >> 3;          // 0..63
    const int sc = tid & 7;           // 0..7 -> k-offsets sc*4..sc*4+3
    const float* asrc = A + ((size_t)g * 64 + st) * HIDDEN + sc * 4;

    float* buf0 = smem;               // [32][68]
    float* buf1 = smem + BK * LDA;

    float acc[8][8];
    #pragma unroll
    for (int i = 0; i < 8; ++i)
        #pragma unroll
        for (int j = 0; j < 8; ++j) acc[i][j] = 0.f;

    #define FMA_TILE(A0, A1, W0, W1) do {                                   \
        float axx[8] = {(A0).x,(A0).y,(A0).z,(A0).w,(A1).x,(A1).y,(A1).z,(A1).w}; \
        float wxx[8] = {(W0).x,(W0).y,(W0).z,(W0).w,(W1).x,(W1).y,(W1).z,(W1).w}; \
        _Pragma("unroll")                                                   \
        for (int i_ = 0; i_ < 8; ++i_)                                      \
            _Pragma("unroll")                                               \
            for (int j_ = 0; j_ < 8; ++j_)                                  \
                acc[i_][j_] = fmaf(axx[i_], wxx[j_], acc[i_][j_]);          \
    } while (0)

    // consume (WC0,WC1) on k-row KK of cb, prefetch next W pair from PP
    #define KSTEP(cb, KK, WC0, WC1, PP) do {                                \
        const float* ar_ = (cb) + (KK) * LDA + tg * 8;                      \
        float4 a0_ = *(const float4*)(ar_);                                 \
        float4 a1_ = *(const float4*)(ar_ + 4);                             \
        float4 p0_ = *(const float4*)((PP) + e0);                           \
        float4 p1_ = *(const float4*)((PP) + e0 + 4);                       \
        FMA_TILE(a0_, a1_, WC0, WC1);                                       \
        WC0 = p0_; WC1 = p1_;                                               \
    } while (0)

    // prologue: stage window 0, prime W k0/k1
    {
        float4 sv = *(const float4*)(asrc);
        buf0[(sc * 4 + 0) * LDA + st] = sv.x;
        buf0[(sc * 4 + 1) * LDA + st] = sv.y;
        buf0[(sc * 4 + 2) * LDA + st] = sv.z;
        buf0[(sc * 4 + 3) * LDA + st] = sv.w;
    }
    const float* wp0 = wT + (size_t)(wv * 4) * 64;
    float4 wa0 = *(const float4*)(wp0 + e0);
    float4 wa1 = *(const float4*)(wp0 + e0 + 4);
    float4 wb0 = *(const float4*)(wp0 + 64 + e0);
    float4 wb1 = *(const float4*)(wp0 + 64 + e0 + 4);

    #pragma unroll 1
    for (int s = 0; s < NSTEP; ++s) {
        float* cb = (s & 1) ? buf1 : buf0;
        float* nb = (s & 1) ? buf0 : buf1;
        __syncthreads();                          // cb published

        float4 snext = make_float4(0.f, 0.f, 0.f, 0.f);
        if (s + 1 < NSTEP) snext = *(const float4*)(asrc + (s + 1) * BK);

        const float* wp  = wT + ((size_t)(s * BK) + wv * 4) * 64;              // this window
        const float* wpn = wT + ((size_t)(((s + 1) & 63) * BK) + wv * 4) * 64; // next window

        const int kb = wv * 4;
        KSTEP(cb, kb + 0, wa0, wa1, wp + 128);    // consume k0, prefetch k2
        KSTEP(cb, kb + 1, wb0, wb1, wp + 192);    // consume k1, prefetch k3
        KSTEP(cb, kb + 2, wa0, wa1, wpn);         // consume k2, prefetch next k0
        KSTEP(cb, kb + 3, wb0, wb1, wpn + 64);    // consume k3, prefetch next k1

        if (s + 1 < NSTEP) {
            nb[(sc * 4 + 0) * LDA + st] = snext.x;
            nb[(sc * 4 + 1) * LDA + st] = snext.y;
            nb[(sc * 4 + 2) * LDA + st] = snext.z;
            nb[(sc * 4 + 3) * LDA + st] = snext.w;
        }
    }
    #undef KSTEP
    #undef FMA_TILE

    // ---- reduce 8 wave-partials into red0 (+bias), paired-wave rounds ----
    float* red0 = smem;
    float* red1 = smem + 4096;
    float* scat = smem + 8192;       // [64 t][65]

    #define PWRITE(dst) do { _Pragma("unroll")                              \
        for (int j_ = 0; j_ < 8; ++j_) {                                    \
            *(float4*)((dst) + (e0 + j_) * 64 + tg * 8) =                   \
                make_float4(acc[0][j_], acc[1][j_], acc[2][j_], acc[3][j_]);\
            *(float4*)((dst) + (e0 + j_) * 64 + tg * 8 + 4) =               \
                make_float4(acc[4][j_], acc[5][j_], acc[6][j_], acc[7][j_]);\
        } } while (0)
    #define PADD(dst) do { _Pragma("unroll")                                \
        for (int j_ = 0; j_ < 8; ++j_) {                                    \
            float4 q0 = *(const float4*)((dst) + (e0 + j_) * 64 + tg * 8);  \
            float4 q1 = *(const float4*)((dst) + (e0 + j_) * 64 + tg * 8 + 4);\
            q0.x += acc[0][j_]; q0.y += acc[1][j_];                         \
            q0.z += acc[2][j_]; q0.w += acc[3][j_];                         \
            q1.x += acc[4][j_]; q1.y += acc[5][j_];                         \
            q1.z += acc[6][j_]; q1.w += acc[7][j_];                         \
            *(float4*)((dst) + (e0 + j_) * 64 + tg * 8)     = q0;           \
            *(float4*)((dst) + (e0 + j_) * 64 + tg * 8 + 4) = q1;           \
        } } while (0)

    __syncthreads();                 // all compute + last reads of buffers done
    if (wv == 0) PWRITE(red0); else if (wv == 1) PWRITE(red1);
    __syncthreads();
    if (wv == 2) PADD(red0); else if (wv == 3) PADD(red1);
    __syncthreads();
    if (wv == 4) PADD(red0); else if (wv == 5) PADD(red1);
    __syncthreads();
    if (wv == 6) PADD(red0); else if (wv == 7) PADD(red1);
    __syncthreads();
    #undef PWRITE
    #undef PADD

    // final: red0 = red0 + red1 + bias   (e = i>>6 is wave-uniform per pass)
    #pragma unroll
    for (int p = 0; p < 8; ++p) {
        int i = tid + 512 * p;
        red0[i] = red0[i] + red1[i] + bias[i >> 6];
    }
    for (int i = tid; i < 64 * 65; i += 512) scat[i] = 0.f;
    __syncthreads();

    // ---- top-8 + softmax + scatter: one thread per token ----
    if (tid < 64) {
        const int t = tid;
        float v[64];
        #pragma unroll
        for (int e = 0; e < 64; ++e) v[e] = red0[e * 64 + t];

        float tvals[TOPK]; int tix[TOPK]; float probs[TOPK];
        unsigned long long chosen = 0ull;
        #pragma unroll
        for (int j = 0; j < TOPK; ++j) {
            float best = -INFINITY; int bi = 0;
            #pragma unroll
            for (int e = 0; e < 64; ++e) {
                bool ok = ((chosen >> e) & 1ull) == 0ull;
                if (ok && v[e] > best) { best = v[e]; bi = e; }  // strict >: lowest idx on tie
            }
            chosen |= (1ull << bi);
            tvals[j] = best; tix[j] = bi;
        }
        float m = tvals[0];
        float ssum = 0.f;
        #pragma unroll
        for (int j = 0; j < TOPK; ++j) { probs[j] = __expf(tvals[j] - m); ssum += probs[j]; }
        float inv = 1.f / ssum;
        #pragma unroll
        for (int j = 0; j < TOPK; ++j) probs[j] *= inv;

        #pragma unroll
        for (int j = 0; j < TOPK; ++j) scat[t * 65 + tix[j]] = probs[j];

        float* oidx = out + (size_t)TOKENS * EXPERTS;
        const int token = g * 64 + t;
        #pragma unroll
        for (int j = 0; j < TOPK; ++j) oidx[(size_t)token * TOPK + j] = (float)tix[j];
    }
    __syncthreads();

    // ---- coalesced score write: 64 tokens x 64 experts = 1024 float4 ----
    float* oscore = out + (size_t)g * 4096;
    #pragma unroll
    for (int p = 0; p < 2; ++p) {
        int fi  = tid + 512 * p;
        int tok = fi >> 4;
        int es  = (fi & 15) * 4;
        float4 vv;
        vv.x = scat[tok * 65 + es + 0];
        vv.y = scat[tok * 65 + es + 1];
        vv.z = scat[tok * 65 + es + 2];
        vv.w = scat[tok * 65 + es + 3];
        *(float4*)(oscore + (size_t)fi * 4) = vv;
    }
}

extern "C" void kernel_launch(void* const* d_in, const int* in_sizes, int n_in,
                              void* d_out, int out_size, void* d_ws, size_t ws_size,
                              hipStream_t stream) {
    const float* A    = (const float*)d_in[0];   // [32768, 2048] fp32
    const float* W    = (const float*)d_in[1];   // [64, 2048] fp32
    const float* bias = (const float*)d_in[2];   // [64] fp32
    float* out = (float*)d_out;                  // scores (32768*64) ++ idx (32768*8)
    float* wT  = (float*)d_ws;                   // 512 KB scratch

    wt_transpose<<<512, 256, 0, stream>>>(W, wT);
    router_bc<<<TOKENS / 64, 512, 0, stream>>>(A, wT, bias, out);
}